// Round 4
// baseline (3957.376 us; speedup 1.0000x reference)
//
#include <hip/hip_runtime.h>

#define SENT32 0x7FFFFFFF
#define IDMASK 0x1FFFF
#define RSHIFT 17

__device__ __forceinline__ unsigned fkey(float f) {
    unsigned u = __float_as_uint(f);
    return (u & 0x80000000u) ? ~u : (u | 0x80000000u);
}
__device__ __forceinline__ float funkey(unsigned k) {
    unsigned u = (k & 0x80000000u) ? (k & 0x7FFFFFFFu) : ~k;
    return __uint_as_float(u);
}

// ---- 1. elevation: elev = x @ W + b, f64 accumulation, wave-per-row ----
__global__ __launch_bounds__(256) void k_matvec(const float* __restrict__ x,
                                                const float* __restrict__ W,
                                                const float* __restrict__ b,
                                                double* __restrict__ elev64,
                                                float* __restrict__ elev32,
                                                int N, int C) {
    int lane = threadIdx.x & 63;
    int wib  = threadIdx.x >> 6;
    int row  = blockIdx.x * (blockDim.x >> 6) + wib;
    if (row >= N) return;
    const float* xr = x + (size_t)row * C;
    double s = 0.0;
    for (int c = lane; c < C; c += 64) s += (double)xr[c] * (double)W[c];
#pragma unroll
    for (int off = 32; off > 0; off >>= 1) s += __shfl_down(s, off, 64);
    if (lane == 0) {
        double v = s + (double)b[0];
        elev64[row] = v;
        elev32[row] = (float)v;
    }
}

// ---- 2a. edge pass A: packed deg/gt/lt counters + down out-degree ----
__global__ __launch_bounds__(256) void k_edgeA(const int* __restrict__ ei,
                                               const double* __restrict__ elev64,
                                               unsigned* __restrict__ cnt,
                                               int* __restrict__ odeg, int E) {
    int e = blockIdx.x * blockDim.x + threadIdx.x;
    if (e >= E) return;
    int s = ei[e];
    int d = ei[(size_t)E + e];
    double es = elev64[s], ed = elev64[d];
    bool ge = (ed >= es);
    bool le = (ed <= es);
    unsigned pack = (1u << 20) | (ge ? (1u << 10) : 0u) | (le ? 1u : 0u);
    atomicAdd(&cnt[d], pack);
    if (le) atomicAdd(&odeg[s], 1);
}

// ---- 2b. edge pass B: CSR adjacency fill (down edges, grouped by src) ----
__global__ __launch_bounds__(256) void k_fill(const int* __restrict__ ei,
                                              const double* __restrict__ elev64,
                                              int* __restrict__ cursor,
                                              int* __restrict__ adj, int E) {
    int e = blockIdx.x * blockDim.x + threadIdx.x;
    if (e >= E) return;
    int s = ei[e];
    int d = ei[(size_t)E + e];
    if (elev64[d] <= elev64[s]) {
        int pos = atomicAdd(&cursor[s], 1);
        adj[pos] = d;
    }
}

// ---- 3. node pass: peak/trough flags, best init, seed queue with peaks ----
__global__ __launch_bounds__(256) void k_nodes1(const unsigned* __restrict__ cnt,
                                                int* __restrict__ peakflag,
                                                int* __restrict__ best,
                                                float* __restrict__ out_ispeak,
                                                float* __restrict__ out_istrough,
                                                float* __restrict__ out_cb,
                                                int* __restrict__ qs,
                                                int* __restrict__ qbuf, int N) {
    int n = blockIdx.x * blockDim.x + threadIdx.x;
    if (n >= N) return;
    unsigned c = cnt[n];
    unsigned deg = c >> 20, gt = (c >> 10) & 1023u, lt = c & 1023u;
    int pk = (gt == deg) ? 1 : 0;
    int tr = (lt == deg) ? 1 : 0;
    peakflag[n] = pk;
    out_ispeak[n] = (float)pk;
    out_istrough[n] = (float)tr;
    best[n] = pk ? n : SENT32;
    out_cb[n] = -1.0f;
    if (pk) {
        int pos = atomicAdd(&qs[0], 1);
        qbuf[pos] = n;
    }
}

// ---- 4. prefix sums (new_id over peakflag; rowptr over odeg) ----
__global__ __launch_bounds__(256) void k_scan_part(const int* __restrict__ flag,
                                                   int* __restrict__ part, int N) {
    int n = blockIdx.x * 256 + threadIdx.x;
    int f = (n < N) ? flag[n] : 0;
#pragma unroll
    for (int off = 32; off > 0; off >>= 1) f += __shfl_down(f, off, 64);
    __shared__ int ws[4];
    int lane = threadIdx.x & 63, wid = threadIdx.x >> 6;
    if (lane == 0) ws[wid] = f;
    __syncthreads();
    if (threadIdx.x == 0) part[blockIdx.x] = ws[0] + ws[1] + ws[2] + ws[3];
}

__global__ __launch_bounds__(64) void k_scan_offs(const int* __restrict__ part,
                                                  int* __restrict__ offs, int P) {
    int lane = threadIdx.x;
    int chunk = (P + 63) / 64;
    int s0 = lane * chunk, s1 = min(s0 + chunk, P);
    int s = 0;
    for (int j = s0; j < s1; ++j) s += part[j];
    int incl = s;
#pragma unroll
    for (int off = 1; off < 64; off <<= 1) {
        int t = __shfl_up(incl, off, 64);
        if (lane >= off) incl += t;
    }
    int run = incl - s;  // exclusive prefix of this lane's chunk
    for (int j = s0; j < s1; ++j) { offs[j] = run; run += part[j]; }
}

// mode 0: out0[n] = inclusive-1        (new_id)
// mode 1: out0[n] = exclusive, out1[n] = exclusive  (rowptr + cursor)
__global__ __launch_bounds__(256) void k_scan_final(const int* __restrict__ flag,
                                                    const int* __restrict__ offs,
                                                    int* __restrict__ out0,
                                                    int* __restrict__ out1,
                                                    int mode, int N) {
    __shared__ int tmp[256];
    int n = blockIdx.x * 256 + threadIdx.x;
    int f = (n < N) ? flag[n] : 0;
    tmp[threadIdx.x] = f;
    __syncthreads();
    for (int off = 1; off < 256; off <<= 1) {
        int t = (threadIdx.x >= off) ? tmp[threadIdx.x - off] : 0;
        __syncthreads();
        tmp[threadIdx.x] += t;
        __syncthreads();
    }
    if (n < N) {
        int incl = offs[blockIdx.x] + tmp[threadIdx.x];
        if (mode == 0) {
            out0[n] = incl - 1;
        } else {
            int excl = incl - f;
            out0[n] = excl;
            out1[n] = excl;
        }
    }
}

// ---- 5. watershed flood fill: async work-queue lexicographic-min fixpoint ----
// best[v] = (d<<17)|label; relax: atomicMin(best[v], best[u]+(1<<17)) over
// down-edges u->v. Least fixpoint == reference's synchronous iteration.
// Queue counters (separate cache lines): qs[0]=tail, qs[32]=claimed,
// qs[64]=completed(+dropped). Termination: completed >= tail, with completed
// read BEFORE tail (both monotone -> stable terminal state; any pushed,
// unprocessed item keeps completed < tail, so no early exit).
// Wave-uniform consumer loop: ready lanes process immediately (no cross-lane
// blocking); wave claims next 64 slots only when current 64 are done.
__global__ __launch_bounds__(256) void k_relax(const int* __restrict__ rowptr,
                                               const int* __restrict__ odeg,
                                               const int* __restrict__ adj,
                                               int* __restrict__ best,
                                               int* __restrict__ qbuf,
                                               int* __restrict__ qs, int qcap) {
    const int lane = threadIdx.x & 63;
    bool term = false;
    int idle = 0;       // total idle iterations across whole kernel (time guard)
    int batches = 0;
    while (!term && ++batches < (1 << 16)) {
        int base = 0;
        if (lane == 0) base = atomicAdd(&qs[32], 64);
        base = __shfl(base, 0, 64);
        const int pos = base + lane;
        bool mine_done = (pos >= qcap);  // virtual (dropped) slots: skip, already counted
        for (;;) {
            int tail = __hip_atomic_load(&qs[0], __ATOMIC_ACQUIRE, __HIP_MEMORY_SCOPE_AGENT);
            int u = -1;
            if (!mine_done && pos < tail)
                u = __hip_atomic_load(&qbuf[pos], __ATOMIC_ACQUIRE, __HIP_MEMORY_SCOPE_AGENT);
            bool ready = (u >= 0);
            if (ready) {
                int ku = __hip_atomic_load(&best[u], __ATOMIC_RELAXED, __HIP_MEMORY_SCOPE_AGENT);
                int cand = ku + (1 << RSHIFT);
                int a = rowptr[u];
                int m = odeg[u];
                for (int j = 0; j < m; ++j) {
                    int v = adj[a + j];
                    int pv = __hip_atomic_load(&best[v], __ATOMIC_RELAXED, __HIP_MEMORY_SCOPE_AGENT);
                    bool imp = false;
                    if (pv > cand) {
                        int old = atomicMin(&best[v], cand);
                        imp = (old > cand);
                    }
                    unsigned long long mk = __ballot(imp);
                    if (mk) {
                        int ldr = __ffsll(mk) - 1;
                        int bp = 0;
                        if (lane == ldr) bp = atomicAdd(&qs[0], __popcll(mk));
                        bp = __shfl(bp, ldr, 64);
                        if (imp) {
                            int rank = __popcll(mk & ((1ull << lane) - 1));
                            int p2 = bp + rank;
                            if (p2 < qcap)
                                __hip_atomic_store(&qbuf[p2], v, __ATOMIC_RELEASE,
                                                   __HIP_MEMORY_SCOPE_AGENT);
                            else
                                atomicAdd(&qs[64], 1);  // dropped: keep balance
                        }
                    }
                }
                mine_done = true;
            }
            unsigned long long cm = __ballot(ready);
            if (cm) {
                int ldr = __ffsll(cm) - 1;
                if (lane == ldr) atomicAdd(&qs[64], __popcll(cm));
            }
            if (__all(mine_done)) break;  // claim next batch
            // termination check: completed first, then tail
            int comp = __hip_atomic_load(&qs[64], __ATOMIC_ACQUIRE, __HIP_MEMORY_SCOPE_AGENT);
            int tail2 = __hip_atomic_load(&qs[0], __ATOMIC_ACQUIRE, __HIP_MEMORY_SCOPE_AGENT);
            if (comp >= tail2) { term = true; break; }
            if (++idle > (1 << 20)) { term = true; break; }  // hard time guard ~80ms
            __builtin_amdgcn_s_sleep(4);
        }
    }
}

// ---- 6. seg labels, segment max, cluster_batch scatter ----
__global__ __launch_bounds__(256) void k_seg(const int* __restrict__ best,
                                             const int* __restrict__ new_id,
                                             const float* __restrict__ elev32,
                                             const int* __restrict__ batch,
                                             int* __restrict__ seg,
                                             float* __restrict__ out_seg,
                                             unsigned* __restrict__ segmax,
                                             float* __restrict__ out_cb, int N) {
    int n = blockIdx.x * blockDim.x + threadIdx.x;
    if (n >= N) return;
    int a = best[n];
    int sg = 0;
    if (a != SENT32) {
        sg = new_id[a & IDMASK];
        atomicMax(&segmax[sg], fkey(elev32[n]));
        if ((a >> RSHIFT) == 0) out_cb[sg] = (float)batch[n];  // peak node
    }
    seg[n] = sg;
    out_seg[n] = (float)sg;
}

// ---- 7. softmax weights + denominator ----
__global__ __launch_bounds__(256) void k_w(const int* __restrict__ best,
                                           const int* __restrict__ seg,
                                           const float* __restrict__ elev32,
                                           const unsigned* __restrict__ segmax,
                                           float* __restrict__ wbuf,
                                           float* __restrict__ z, int N) {
    int n = blockIdx.x * blockDim.x + threadIdx.x;
    if (n >= N) return;
    int a = best[n];
    int sg = seg[n];
    float wv = 0.0f;
    if (a != SENT32) {
        float smax = funkey(segmax[sg]);
        wv = expf(elev32[n] - smax);
        atomicAdd(&z[sg], wv);
    }
    wbuf[n] = wv;
}

// ---- 8. scaling + weighted pooling (wave-per-node) ----
__global__ __launch_bounds__(256) void k_pool(const float* __restrict__ x,
                                              const int* __restrict__ seg,
                                              const float* __restrict__ wbuf,
                                              const float* __restrict__ z,
                                              float* __restrict__ out_scaling,
                                              float* __restrict__ out_pooled,
                                              int N, int C) {
    int lane = threadIdx.x & 63;
    int node = blockIdx.x * (blockDim.x >> 6) + (threadIdx.x >> 6);
    if (node >= N) return;
    int sg = seg[node];
    float sc = wbuf[node] / (z[sg] + 1e-12f);
    if (lane == 0) out_scaling[node] = sc;
    const float* xr = x + (size_t)node * C;
    float* pr = out_pooled + (size_t)sg * C;
    for (int c = lane; c < C; c += 64) atomicAdd(&pr[c], xr[c] * sc);
}

extern "C" void kernel_launch(void* const* d_in, const int* in_sizes, int n_in,
                              void* d_out, int out_size, void* d_ws, size_t ws_size,
                              hipStream_t stream) {
    const float* x = (const float*)d_in[0];
    const float* W = (const float*)d_in[1];
    const float* b = (const float*)d_in[2];
    const int* ei = (const int*)d_in[3];
    const int* batch = (const int*)d_in[4];

    const int C = in_sizes[1];           // 128
    const int N = in_sizes[0] / C;       // 100000
    const int E = in_sizes[3] / 2;       // 3200000

    float* out_pooled   = (float*)d_out;
    float* out_seg      = out_pooled + (size_t)N * C;
    float* out_scaling  = out_seg + N;
    float* out_cb       = out_scaling + N;
    float* out_ispeak   = out_cb + N;
    float* out_istrough = out_ispeak + N;

    char* p = (char*)d_ws;
    auto alloc = [&](size_t bytes) -> char* {
        char* r = p;
        p += (bytes + 255) & ~(size_t)255;
        return r;
    };
    double* elev64 = (double*)alloc((size_t)N * 8);
    float* elev32  = (float*)alloc((size_t)N * 4);
    int* best      = (int*)alloc((size_t)N * 4);
    int* peakflag  = (int*)alloc((size_t)N * 4);
    int* new_id    = (int*)alloc((size_t)N * 4);
    int* seg       = (int*)alloc((size_t)N * 4);
    float* wbuf    = (float*)alloc((size_t)N * 4);
    int* rowptr    = (int*)alloc((size_t)N * 4);
    int* cursor    = (int*)alloc((size_t)N * 4);
    const int P = (N + 255) / 256;
    int* part = (int*)alloc((size_t)P * 4);
    int* offs = (int*)alloc((size_t)P * 4);
    char* zbeg = p;  // zero-initialized region starts here
    unsigned* cnt    = (unsigned*)alloc((size_t)N * 4);
    unsigned* segmax = (unsigned*)alloc((size_t)N * 4);
    float* z         = (float*)alloc((size_t)N * 4);
    int* odeg        = (int*)alloc((size_t)N * 4);
    int* qs          = (int*)alloc(512);
    size_t zspan = (size_t)(p - zbeg);
    int* adj  = (int*)alloc((size_t)E * 4);
    const int qcap = 24 * N;            // 2.4M entries, ~9.6 MB
    int* qbuf = (int*)alloc((size_t)qcap * 4);
    (void)ws_size;

    hipMemsetAsync(out_pooled, 0, (size_t)N * C * sizeof(float), stream);
    hipMemsetAsync(zbeg, 0, zspan, stream);
    hipMemsetAsync(qbuf, 0xFF, (size_t)qcap * 4, stream);

    k_matvec<<<(N + 3) / 4, 256, 0, stream>>>(x, W, b, elev64, elev32, N, C);
    k_edgeA<<<(E + 255) / 256, 256, 0, stream>>>(ei, elev64, cnt, odeg, E);
    k_nodes1<<<(N + 255) / 256, 256, 0, stream>>>(cnt, peakflag, best, out_ispeak,
                                                  out_istrough, out_cb, qs, qbuf, N);
    // new_id = inclusive_scan(peakflag) - 1
    k_scan_part<<<P, 256, 0, stream>>>(peakflag, part, N);
    k_scan_offs<<<1, 64, 0, stream>>>(part, offs, P);
    k_scan_final<<<P, 256, 0, stream>>>(peakflag, offs, new_id, nullptr, 0, N);
    // rowptr/cursor = exclusive_scan(odeg)
    k_scan_part<<<P, 256, 0, stream>>>(odeg, part, N);
    k_scan_offs<<<1, 64, 0, stream>>>(part, offs, P);
    k_scan_final<<<P, 256, 0, stream>>>(odeg, offs, rowptr, cursor, 1, N);

    k_fill<<<(E + 255) / 256, 256, 0, stream>>>(ei, elev64, cursor, adj, E);

    k_relax<<<256, 256, 0, stream>>>(rowptr, odeg, adj, best, qbuf, qs, qcap);

    k_seg<<<(N + 255) / 256, 256, 0, stream>>>(best, new_id, elev32, batch, seg,
                                               out_seg, segmax, out_cb, N);
    k_w<<<(N + 255) / 256, 256, 0, stream>>>(best, seg, elev32, segmax, wbuf, z, N);
    k_pool<<<(N + 3) / 4, 256, 0, stream>>>(x, seg, wbuf, z, out_scaling, out_pooled, N, C);
}

// Round 5
// 996.956 us; speedup vs baseline: 3.9695x; 3.9695x over previous
//
#include <hip/hip_runtime.h>

#define SENT32 0x7FFFFFFF
#define IDMASK 0x1FFFF
#define RSHIFT 17
#define NLEVELS 14

__device__ __forceinline__ unsigned fkey(float f) {
    unsigned u = __float_as_uint(f);
    return (u & 0x80000000u) ? ~u : (u | 0x80000000u);
}
__device__ __forceinline__ float funkey(unsigned k) {
    unsigned u = (k & 0x80000000u) ? (k & 0x7FFFFFFFu) : ~k;
    return __uint_as_float(u);
}

// ---- 1. elevation: elev = x @ W + b, f64 accumulation, wave-per-row ----
__global__ __launch_bounds__(256) void k_matvec(const float* __restrict__ x,
                                                const float* __restrict__ W,
                                                const float* __restrict__ b,
                                                double* __restrict__ elev64,
                                                float* __restrict__ elev32,
                                                int N, int C) {
    int lane = threadIdx.x & 63;
    int wib  = threadIdx.x >> 6;
    int row  = blockIdx.x * (blockDim.x >> 6) + wib;
    if (row >= N) return;
    const float* xr = x + (size_t)row * C;
    double s = 0.0;
    for (int c = lane; c < C; c += 64) s += (double)xr[c] * (double)W[c];
#pragma unroll
    for (int off = 32; off > 0; off >>= 1) s += __shfl_down(s, off, 64);
    if (lane == 0) {
        double v = s + (double)b[0];
        elev64[row] = v;
        elev32[row] = (float)v;
    }
}

// ---- 2. edge pass: peak/trough violation marks + compact down-edge list ----
__global__ __launch_bounds__(256) void k_edgeA(const int* __restrict__ ei,
                                               const double* __restrict__ elev64,
                                               unsigned char* __restrict__ notpeak,
                                               unsigned char* __restrict__ nottrough,
                                               int2* __restrict__ down,
                                               int* __restrict__ dcount, int E) {
    __shared__ int wcnt[4];
    __shared__ int wbase[4];
    int e = blockIdx.x * 256 + threadIdx.x;
    int lane = threadIdx.x & 63, wid = threadIdx.x >> 6;
    int s = 0, d = 0;
    bool le = false;
    if (e < E) {
        s = ei[e];
        d = ei[(size_t)E + e];
        double es = elev64[s], ed = elev64[d];
        if (ed < es) notpeak[d] = 1;    // violates "d >= all neighbors"
        if (ed > es) nottrough[d] = 1;  // violates "d <= all neighbors"
        le = (ed <= es);                // down edge s->d
    }
    unsigned long long mk = __ballot(le);
    int rank = __popcll(mk & ((1ull << lane) - 1));
    if (lane == 0) wcnt[wid] = __popcll(mk);
    __syncthreads();
    if (threadIdx.x == 0) {
        int t = wcnt[0] + wcnt[1] + wcnt[2] + wcnt[3];
        int bse = t ? atomicAdd(dcount, t) : 0;
        wbase[0] = bse;
        wbase[1] = bse + wcnt[0];
        wbase[2] = wbase[1] + wcnt[1];
        wbase[3] = wbase[2] + wcnt[2];
    }
    __syncthreads();
    if (le) down[wbase[wid] + rank] = make_int2(s, d);
}

// ---- 3. node pass: peak/trough flags, best init, count peaks ----
__global__ __launch_bounds__(256) void k_nodes1(const unsigned char* __restrict__ notpeak,
                                                const unsigned char* __restrict__ nottrough,
                                                int* __restrict__ peakflag,
                                                int* __restrict__ best,
                                                float* __restrict__ out_ispeak,
                                                float* __restrict__ out_istrough,
                                                float* __restrict__ out_cb,
                                                int* __restrict__ nassigned, int N) {
    int n = blockIdx.x * blockDim.x + threadIdx.x;
    int lane = threadIdx.x & 63;
    bool in = (n < N);
    int pk = 0;
    if (in) {
        pk = notpeak[n] ? 0 : 1;
        int tr = nottrough[n] ? 0 : 1;
        peakflag[n] = pk;
        out_ispeak[n] = (float)pk;
        out_istrough[n] = (float)tr;
        best[n] = pk ? n : SENT32;
        out_cb[n] = -1.0f;
    }
    unsigned long long mk = __ballot(pk);
    if (mk) {
        int ldr = __ffsll(mk) - 1;
        if (lane == ldr) atomicAdd(&nassigned[0], __popcll(mk));
    }
}

// ---- 4. prefix sums ----
__global__ __launch_bounds__(256) void k_scan_part(const int* __restrict__ flag,
                                                   int* __restrict__ part, int N) {
    int n = blockIdx.x * 256 + threadIdx.x;
    int f = (n < N) ? flag[n] : 0;
#pragma unroll
    for (int off = 32; off > 0; off >>= 1) f += __shfl_down(f, off, 64);
    __shared__ int ws[4];
    int lane = threadIdx.x & 63, wid = threadIdx.x >> 6;
    if (lane == 0) ws[wid] = f;
    __syncthreads();
    if (threadIdx.x == 0) part[blockIdx.x] = ws[0] + ws[1] + ws[2] + ws[3];
}

__global__ __launch_bounds__(64) void k_scan_offs(const int* __restrict__ part,
                                                  int* __restrict__ offs, int P) {
    int lane = threadIdx.x;
    int chunk = (P + 63) / 64;
    int s0 = lane * chunk, s1 = min(s0 + chunk, P);
    int s = 0;
    for (int j = s0; j < s1; ++j) s += part[j];
    int incl = s;
#pragma unroll
    for (int off = 1; off < 64; off <<= 1) {
        int t = __shfl_up(incl, off, 64);
        if (lane >= off) incl += t;
    }
    int run = incl - s;
    for (int j = s0; j < s1; ++j) { offs[j] = run; run += part[j]; }
}

// mode 0: out0[n] = inclusive-1; mode 1: out0[n] = out1[n] = exclusive
__global__ __launch_bounds__(256) void k_scan_final(const int* __restrict__ flag,
                                                    const int* __restrict__ offs,
                                                    int* __restrict__ out0,
                                                    int* __restrict__ out1,
                                                    int mode, int N) {
    __shared__ int tmp[256];
    int n = blockIdx.x * 256 + threadIdx.x;
    int f = (n < N) ? flag[n] : 0;
    tmp[threadIdx.x] = f;
    __syncthreads();
    for (int off = 1; off < 256; off <<= 1) {
        int t = (threadIdx.x >= off) ? tmp[threadIdx.x - off] : 0;
        __syncthreads();
        tmp[threadIdx.x] += t;
        __syncthreads();
    }
    if (n < N) {
        int incl = offs[blockIdx.x] + tmp[threadIdx.x];
        if (mode == 0) {
            out0[n] = incl - 1;
        } else {
            int excl = incl - f;
            out0[n] = excl;
            out1[n] = excl;
        }
    }
}

// ---- 5. one BFS level, sync via kernel boundary ----
// Parents qualify iff round(best[src]) == L-1 (stable values this kernel);
// same-kernel writes carry round L and self-exclude -> race-free level.
__global__ __launch_bounds__(256) void k_level(const int2* __restrict__ down,
                                               const int* __restrict__ p_nd,
                                               int* __restrict__ best,
                                               int* __restrict__ nassigned, int L) {
    if (nassigned[L - 1] == 0) return;  // converged: nothing assigned last level
    int nd = *p_nd;
    int lane = threadIdx.x & 63;
    int stride = gridDim.x * blockDim.x;
    for (int e0 = blockIdx.x * blockDim.x; e0 < nd; e0 += stride) {
        int e = e0 + threadIdx.x;
        bool first = false;
        if (e < nd) {
            int2 ed = down[e];
            int bs = best[ed.x];
            if ((bs >> RSHIFT) == L - 1) {
                int cand = (L << RSHIFT) | (bs & IDMASK);
                int bd = best[ed.y];
                if (bd > cand) {
                    int old = atomicMin(&best[ed.y], cand);
                    first = (old == SENT32);
                }
            }
        }
        unsigned long long mk = __ballot(first);
        if (mk) {
            int ldr = __ffsll(mk) - 1;
            if (lane == ldr) atomicAdd(&nassigned[L], __popcll(mk));
        }
    }
}

// ---- 5b. safety net: finish any levels beyond NLEVELS in one block ----
__global__ __launch_bounds__(1024) void k_tail(const int2* __restrict__ down,
                                               const int* __restrict__ p_nd,
                                               int* __restrict__ best,
                                               int* __restrict__ nassigned) {
    int nd = *p_nd;
    for (int L = NLEVELS + 1; L < 3000; ++L) {
        if (__hip_atomic_load(&nassigned[L - 1], __ATOMIC_RELAXED,
                              __HIP_MEMORY_SCOPE_AGENT) == 0) return;
        for (int e = threadIdx.x; e < nd; e += blockDim.x) {
            int2 ed = down[e];
            int bs = __hip_atomic_load(&best[ed.x], __ATOMIC_RELAXED,
                                       __HIP_MEMORY_SCOPE_AGENT);
            if ((bs >> RSHIFT) == L - 1) {
                int cand = (L << RSHIFT) | (bs & IDMASK);
                int bd = __hip_atomic_load(&best[ed.y], __ATOMIC_RELAXED,
                                           __HIP_MEMORY_SCOPE_AGENT);
                if (bd > cand) {
                    int old = atomicMin(&best[ed.y], cand);
                    if (old == SENT32) atomicAdd(&nassigned[L], 1);
                }
            }
        }
        __threadfence();
        __syncthreads();
    }
}

// ---- 6. seg labels, segment max, cluster_batch, cluster histogram ----
__global__ __launch_bounds__(256) void k_seg(const int* __restrict__ best,
                                             const int* __restrict__ new_id,
                                             const float* __restrict__ elev32,
                                             const int* __restrict__ batch,
                                             int* __restrict__ seg,
                                             float* __restrict__ out_seg,
                                             unsigned* __restrict__ segmax,
                                             float* __restrict__ out_cb,
                                             int* __restrict__ hist, int N) {
    int n = blockIdx.x * blockDim.x + threadIdx.x;
    if (n >= N) return;
    int a = best[n];
    int sg = 0;
    if (a != SENT32) {
        sg = new_id[a & IDMASK];
        atomicMax(&segmax[sg], fkey(elev32[n]));
        if ((a >> RSHIFT) == 0) out_cb[sg] = (float)batch[n];  // peak node
    }
    seg[n] = sg;
    out_seg[n] = (float)sg;
    atomicAdd(&hist[sg], 1);
}

// ---- 6b. cluster member-list fill ----
__global__ __launch_bounds__(256) void k_cfill(const int* __restrict__ seg,
                                               int* __restrict__ ccursor,
                                               int* __restrict__ members, int N) {
    int n = blockIdx.x * blockDim.x + threadIdx.x;
    if (n >= N) return;
    int pos = atomicAdd(&ccursor[seg[n]], 1);
    members[pos] = n;
}

// ---- 7. softmax weights + denominator ----
__global__ __launch_bounds__(256) void k_w(const int* __restrict__ best,
                                           const int* __restrict__ seg,
                                           const float* __restrict__ elev32,
                                           const unsigned* __restrict__ segmax,
                                           float* __restrict__ wbuf,
                                           float* __restrict__ z, int N) {
    int n = blockIdx.x * blockDim.x + threadIdx.x;
    if (n >= N) return;
    int a = best[n];
    int sg = seg[n];
    float wv = 0.0f;
    if (a != SENT32) {
        float smax = funkey(segmax[sg]);
        wv = expf(elev32[n] - smax);
        atomicAdd(&z[sg], wv);
    }
    wbuf[n] = wv;
}

// ---- 8. wave-per-cluster pooling: zero atomics, one row write/cluster ----
__global__ __launch_bounds__(256) void k_pool2(const float* __restrict__ x,
                                               const int* __restrict__ members,
                                               const int* __restrict__ cstart,
                                               const int* __restrict__ hist,
                                               const float* __restrict__ wbuf,
                                               const float* __restrict__ z,
                                               const int* __restrict__ p_K,
                                               float* __restrict__ out_scaling,
                                               float* __restrict__ out_pooled, int C) {
    int lane = threadIdx.x & 63;
    int w = blockIdx.x * (blockDim.x >> 6) + (threadIdx.x >> 6);
    int nw = gridDim.x * (blockDim.x >> 6);
    int K = *p_K;
    int c1 = lane + 64;
    for (int cl = w; cl < K; cl += nw) {
        int s0 = cstart[cl], cnt = hist[cl];
        float zz = z[cl] + 1e-12f;
        float a0 = 0.0f, a1 = 0.0f;
        for (int j = 0; j < cnt; ++j) {
            int m = members[s0 + j];
            float sc = wbuf[m] / zz;
            const float* xr = x + (size_t)m * C;
            a0 += xr[lane] * sc;
            if (c1 < C) a1 += xr[c1] * sc;
            if (lane == 0) out_scaling[m] = sc;
        }
        float* pr = out_pooled + (size_t)cl * C;
        pr[lane] = a0;
        if (c1 < C) pr[c1] = a1;
    }
}

extern "C" void kernel_launch(void* const* d_in, const int* in_sizes, int n_in,
                              void* d_out, int out_size, void* d_ws, size_t ws_size,
                              hipStream_t stream) {
    const float* x = (const float*)d_in[0];
    const float* W = (const float*)d_in[1];
    const float* b = (const float*)d_in[2];
    const int* ei = (const int*)d_in[3];
    const int* batch = (const int*)d_in[4];

    const int C = in_sizes[1];           // 128
    const int N = in_sizes[0] / C;       // 100000
    const int E = in_sizes[3] / 2;       // 3200000

    float* out_pooled   = (float*)d_out;
    float* out_seg      = out_pooled + (size_t)N * C;
    float* out_scaling  = out_seg + N;
    float* out_cb       = out_scaling + N;
    float* out_ispeak   = out_cb + N;
    float* out_istrough = out_ispeak + N;

    char* p = (char*)d_ws;
    auto alloc = [&](size_t bytes) -> char* {
        char* r = p;
        p += (bytes + 255) & ~(size_t)255;
        return r;
    };
    double* elev64 = (double*)alloc((size_t)N * 8);
    float* elev32  = (float*)alloc((size_t)N * 4);
    int* best      = (int*)alloc((size_t)N * 4);
    int* peakflag  = (int*)alloc((size_t)N * 4);
    int* new_id    = (int*)alloc((size_t)N * 4);
    int* seg       = (int*)alloc((size_t)N * 4);
    float* wbuf    = (float*)alloc((size_t)N * 4);
    int* members   = (int*)alloc((size_t)N * 4);
    int* cstart    = (int*)alloc((size_t)N * 4);
    int* ccursor   = (int*)alloc((size_t)N * 4);
    const int P = (N + 255) / 256;
    int* part = (int*)alloc((size_t)P * 4);
    int* offs = (int*)alloc((size_t)P * 4);
    char* zbeg = p;  // zero-initialized region starts here
    unsigned char* notpeak   = (unsigned char*)alloc((size_t)N);
    unsigned char* nottrough = (unsigned char*)alloc((size_t)N);
    unsigned* segmax = (unsigned*)alloc((size_t)N * 4);
    float* z         = (float*)alloc((size_t)N * 4);
    int* hist        = (int*)alloc((size_t)N * 4);
    int* nassigned   = (int*)alloc(3072 * 4);
    int* dcount      = (int*)alloc(256);
    size_t zspan = (size_t)(p - zbeg);
    int2* down = (int2*)alloc((size_t)E * 8);
    (void)ws_size;

    hipMemsetAsync(out_pooled, 0, (size_t)N * C * sizeof(float), stream);
    hipMemsetAsync(zbeg, 0, zspan, stream);

    k_matvec<<<(N + 3) / 4, 256, 0, stream>>>(x, W, b, elev64, elev32, N, C);
    k_edgeA<<<(E + 255) / 256, 256, 0, stream>>>(ei, elev64, notpeak, nottrough,
                                                 down, dcount, E);
    k_nodes1<<<(N + 255) / 256, 256, 0, stream>>>(notpeak, nottrough, peakflag, best,
                                                  out_ispeak, out_istrough, out_cb,
                                                  nassigned, N);
    // new_id = inclusive_scan(peakflag) - 1
    k_scan_part<<<P, 256, 0, stream>>>(peakflag, part, N);
    k_scan_offs<<<1, 64, 0, stream>>>(part, offs, P);
    k_scan_final<<<P, 256, 0, stream>>>(peakflag, offs, new_id, nullptr, 0, N);

    // BFS levels: kernel-boundary-synchronized, early-exit when converged
    for (int L = 1; L <= NLEVELS; ++L)
        k_level<<<1024, 256, 0, stream>>>(down, dcount, best, nassigned, L);
    k_tail<<<1, 1024, 0, stream>>>(down, dcount, best, nassigned);

    k_seg<<<(N + 255) / 256, 256, 0, stream>>>(best, new_id, elev32, batch, seg,
                                               out_seg, segmax, out_cb, hist, N);
    // cstart/ccursor = exclusive_scan(hist)
    k_scan_part<<<P, 256, 0, stream>>>(hist, part, N);
    k_scan_offs<<<1, 64, 0, stream>>>(part, offs, P);
    k_scan_final<<<P, 256, 0, stream>>>(hist, offs, cstart, ccursor, 1, N);
    k_cfill<<<(N + 255) / 256, 256, 0, stream>>>(seg, ccursor, members, N);

    k_w<<<(N + 255) / 256, 256, 0, stream>>>(best, seg, elev32, segmax, wbuf, z, N);
    k_pool2<<<512, 256, 0, stream>>>(x, members, cstart, hist, wbuf, z,
                                     nassigned, out_scaling, out_pooled, C);
}